// Round 17
// baseline (481.438 us; speedup 1.0000x reference)
//
#include <hip/hip_runtime.h>
#include <hip/hip_bf16.h>
#include <math.h>

#define D_MODEL 256
#define D_STATE 16
#define D_INNER 512
#define DT_RANK 16
#define NB 4
#define NVAR 32
#define SEG 96
#define TOKENS (NB*NVAR*SEG)   /* 12288 */

typedef float f4 __attribute__((ext_vector_type(4)));

__device__ __forceinline__ float silu_f(float x) { return x / (1.0f + __expf(-x)); }

// ---------------------------------------------------------------------------
// WT[k][n] = W[n][k].  W: [N][K].  grid (K/32, N/32), block 256.
// ---------------------------------------------------------------------------
__global__ __launch_bounds__(256)
void transpose_w(const float* __restrict__ W, float* __restrict__ WT, int N, int K)
{
    __shared__ float t[32][33];
    const int k0 = blockIdx.x * 32, n0 = blockIdx.y * 32;
    const int tx = threadIdx.x & 31, ty = threadIdx.x >> 5;
#pragma unroll
    for (int i = 0; i < 32; i += 8)
        t[ty + i][tx] = W[(size_t)(n0 + ty + i) * K + k0 + tx];
    __syncthreads();
#pragma unroll
    for (int i = 0; i < 32; i += 8)
        WT[(size_t)(k0 + ty + i) * N + n0 + tx] = t[tx][ty + i];
}

// ---------------------------------------------------------------------------
// NT GEMM v9: counted-vmcnt pipeline, occupancy-preserving config.
// BN=128, BK=8 -> 4 LDS buffers = 16 KB (same occupancy as the 77us v6),
// J=1 DMA instr/wave/tile.  Per tile:
//   s_waitcnt vmcnt(2)   (own tile done; 2 tiles stay in flight)
//   s_barrier            (tile t resident for all waves)
//   stage(t+3)           (buffer (t-1)&3 provably free; max head start)
//   compute(t)
// vs r16-v8: LDS 32->16KB (occupancy 30->41%), stage moved before compute,
// sched_barrier(0) dropped ("memory" clobber on waitcnt already orders the
// ds_read/s_load; blanket pin hurt scheduling).
// A wave-uniform -> s_load (lgkm; independent of vmcnt -> counting valid).
// MODE 0 plain; 2: rows (b,v,s)->(b,s,v); 3: inverse.  Requires NT >= 4.
// ---------------------------------------------------------------------------
template<int K, int BN, int BK, int MODE>
__global__ __launch_bounds__(256, 4)
void gemm_v9(const float* __restrict__ A, const float* __restrict__ WT,
             float* __restrict__ C, int N)
{
    constexpr int NT  = K / BK;
    constexpr int CPL = BN / 64;                 // 2 for BN=128
    constexpr int KRD = 1024 / (BN * 4);         // k-rows per 1KB DMA: 2
    constexpr int J   = BK / (KRD * 4);          // DMA instrs per wave/tile: 1
    typedef float cvec __attribute__((ext_vector_type(CPL)));
    __shared__ float wlds[4 * BK * BN];

    const int tid  = threadIdx.x;
    const int lane = tid & 63;
    const int wid  = __builtin_amdgcn_readfirstlane(tid >> 6);
    const int m0 = blockIdx.x * 32;
    const int n0 = blockIdx.y * BN;

    // wave-uniform A row pointers -> s_load fragments (scalar pipe)
    const float* Ar[8];
#pragma unroll
    for (int r = 0; r < 8; r++)
        Ar[r] = A + (size_t)(m0 + wid * 8 + r) * K;

    // coalesced DMA: each instr stages KRD k-rows (1 KB) of WT tile kt
    auto stage = [&](int buf, int kt) {
#pragma unroll
        for (int j = 0; j < J; j++) {
            int kb   = (wid * J + j) * KRD;
            int krow = kb + ((KRD == 2) ? (lane >> 5) : 0);
            int nofs = ((KRD == 2) ? (lane & 31) : lane) * 4;
            int dstw = __builtin_amdgcn_readfirstlane(buf * (BK * BN) + kb * BN);
            __builtin_amdgcn_global_load_lds(
                (const __attribute__((address_space(1))) void*)
                    (WT + (size_t)(kt * BK + krow) * N + n0 + nofs),
                (__attribute__((address_space(3))) void*)(wlds + dstw), 16, 0, 0);
        }
    };

    float acc[8][CPL];
#pragma unroll
    for (int r = 0; r < 8; r++)
#pragma unroll
        for (int g = 0; g < CPL; g++) acc[r][g] = 0.0f;

    stage(0, 0);
    stage(1, 1);
    stage(2, 2);

    for (int t = 0; t < NT; t++) {
        // wait own tile-t DMA (J ops); tiles t+1, t+2 stay in flight
        asm volatile("s_waitcnt vmcnt(%0)" :: "i"(2 * J) : "memory");
        __builtin_amdgcn_s_barrier();
        // issue tile t+3 into buffer (t-1)&3 (freed: barrier(t) proves all
        // waves finished compute(t-1)).  Dummy wrap keeps vmcnt uniform.
        int nt3 = t + 3;
        int kt  = (nt3 < NT) ? nt3 : nt3 - NT;
        stage(nt3 & 3, kt);

        const float* Wb = wlds + (t & 3) * (BK * BN);
        const int k0 = t * BK;
#pragma unroll
        for (int q = 0; q < BK / 4; q++) {
            f4 a4[8];
#pragma unroll
            for (int r = 0; r < 8; r++)          // uniform -> s_load_dwordx4
                a4[r] = *(const f4*)(Ar[r] + k0 + 4 * q);
#pragma unroll
            for (int e = 0; e < 4; e++) {
                cvec wv = *(const cvec*)(Wb + (4 * q + e) * BN + CPL * lane);
#pragma unroll
                for (int r = 0; r < 8; r++)
#pragma unroll
                    for (int g = 0; g < CPL; g++)
                        acc[r][g] = fmaf(a4[r][e], wv[g], acc[r][g]);
            }
        }
    }
    // drain before s_endpgm: pending DMA into deallocated LDS is unsafe
    asm volatile("s_waitcnt vmcnt(0)" ::: "memory");

#pragma unroll
    for (int r = 0; r < 8; r++) {
        int m = m0 + wid * 8 + r;
        int orow = m;
        if (MODE == 2) {                         // (b*32+v)*96+s -> (b*96+s)*32+v
            int b = m / 3072, rr = m % 3072;
            int v = rr / 96, s = rr % 96;
            orow = (b * 96 + s) * 32 + v;
        } else if (MODE == 3) {                  // (b*96+s)*32+v -> (b*32+v)*96+s
            int b = m / 3072, rr = m % 3072;
            int s = rr / 32, v = rr % 32;
            orow = (b * 32 + v) * 96 + s;
        }
        cvec v;
#pragma unroll
        for (int g = 0; g < CPL; g++) v[g] = acc[r][g];
        *(cvec*)(C + (size_t)orow * N + n0 + CPL * lane) = v;
    }
}

// ---------------------------------------------------------------------------
// Fused x_proj + dt_proj: one block owns 32 full rows.
// ---------------------------------------------------------------------------
__global__ __launch_bounds__(256)
void xproj_dt(const float* __restrict__ xc,
              const float* __restrict__ xpw,    // [48][512]
              const float* __restrict__ dtw,    // [512][16]
              const float* __restrict__ dtb,    // [512]
              float* __restrict__ dbl,          // [M][48]
              float* __restrict__ dty,          // [M][512]
              int M)
{
    constexpr int BM = 32, BN = 64, BK = 32, TM = 2, TN = 4;
    __shared__ float As[BK][BM + 4];
    __shared__ float Ws[BK][BN + 4];
    __shared__ float dbl_s[BM][52];

    const int tid = threadIdx.x;
    const int tx  = tid % (BN / TN);
    const int ty  = tid / (BN / TN);
    const int m0  = blockIdx.x * BM;

    float acc[TM][TN];
#pragma unroll
    for (int i = 0; i < TM; i++)
#pragma unroll
        for (int j = 0; j < TN; j++) acc[i][j] = 0.0f;

    constexpr int AF4 = (BM * BK) / 1024;
    constexpr int WF4 = (BN * BK) / 1024;
    constexpr int F4R = BK / 4;

    for (int k0 = 0; k0 < 512; k0 += BK) {
#pragma unroll
        for (int c = 0; c < AF4; c++) {
            int idx = tid + c * 256;
            int row = idx / F4R;
            int kc  = (idx % F4R) * 4;
            float4 v = *(const float4*)(xc + (size_t)(m0 + row) * 512 + k0 + kc);
            As[kc + 0][row] = v.x;
            As[kc + 1][row] = v.y;
            As[kc + 2][row] = v.z;
            As[kc + 3][row] = v.w;
        }
#pragma unroll
        for (int c = 0; c < WF4; c++) {
            int idx = tid + c * 256;
            int row = idx / F4R;
            int kc  = (idx % F4R) * 4;
            float4 v;
            if (row < 48) v = *(const float4*)(xpw + (size_t)row * 512 + k0 + kc);
            else          v = make_float4(0.f, 0.f, 0.f, 0.f);
            Ws[kc + 0][row] = v.x;
            Ws[kc + 1][row] = v.y;
            Ws[kc + 2][row] = v.z;
            Ws[kc + 3][row] = v.w;
        }
        __syncthreads();

#pragma unroll
        for (int kk = 0; kk < BK; kk++) {
            float a[TM], w[TN];
#pragma unroll
            for (int i = 0; i < TM; i++) a[i] = As[kk][ty * TM + i];
#pragma unroll
            for (int j = 0; j < TN; j++) w[j] = Ws[kk][tx * TN + j];
#pragma unroll
            for (int i = 0; i < TM; i++)
#pragma unroll
                for (int j = 0; j < TN; j++)
                    acc[i][j] = fmaf(a[i], w[j], acc[i][j]);
        }
        __syncthreads();
    }

#pragma unroll
    for (int i = 0; i < TM; i++) {
        int mr = ty * TM + i;
#pragma unroll
        for (int j = 0; j < TN; j++) {
            int n = tx * TN + j;
            if (n < 48) {
                dbl[(size_t)(m0 + mr) * 48 + n] = acc[i][j];
                dbl_s[mr][n] = acc[i][j];
            }
        }
    }
    __syncthreads();

    f4 wA[4], wB[4];
#pragma unroll
    for (int c = 0; c < 4; c++) {
        wA[c] = *(const f4*)(dtw + (size_t)tid * 16 + 4 * c);
        wB[c] = *(const f4*)(dtw + (size_t)(tid + 256) * 16 + 4 * c);
    }
    const float bA = dtb[tid], bB = dtb[tid + 256];
#pragma unroll 4
    for (int r = 0; r < BM; r++) {
        f4 d[4];
#pragma unroll
        for (int c = 0; c < 4; c++) d[c] = *(const f4*)(&dbl_s[r][4 * c]);
        float vA = bA, vB = bB;
#pragma unroll
        for (int c = 0; c < 4; c++)
#pragma unroll
            for (int e = 0; e < 4; e++) {
                vA = fmaf(d[c][e], wA[c][e], vA);
                vB = fmaf(d[c][e], wB[c][e], vB);
            }
        vA = (vA > 20.0f) ? vA : log1pf(__expf(vA));
        vB = (vB > 20.0f) ? vB : log1pf(__expf(vB));
        dty[(size_t)(m0 + r) * 512 + tid]       = vA;
        dty[(size_t)(m0 + r) * 512 + tid + 256] = vB;
    }
}

// ---------------------------------------------------------------------------
// Depthwise causal conv (width 4) + bias + SiLU, vectorized x4 channels.
// ---------------------------------------------------------------------------
__global__ __launch_bounds__(256)
void conv_silu(const float* __restrict__ xz, const float* __restrict__ cw,
               const float* __restrict__ cb, float* __restrict__ xc, int L)
{
    int i  = blockIdx.x * 256 + threadIdx.x;     // one per 4 channels
    int e4 = (i & 127) << 2;
    int t  = i >> 7;
    int l  = t % L;
    const f4 w0 = *(const f4*)(cw + e4 * 4);
    const f4 w1 = *(const f4*)(cw + e4 * 4 + 4);
    const f4 w2 = *(const f4*)(cw + e4 * 4 + 8);
    const f4 w3 = *(const f4*)(cw + e4 * 4 + 12);
    f4 acc = *(const f4*)(cb + e4);
#pragma unroll
    for (int j = 0; j < 4; j++) {
        int li = l - 3 + j;
        if (li >= 0) {
            f4 xv = *(const f4*)(xz + (size_t)(t + li - l) * 1024 + e4);
            acc[0] = fmaf(xv[0], w0[j], acc[0]);
            acc[1] = fmaf(xv[1], w1[j], acc[1]);
            acc[2] = fmaf(xv[2], w2[j], acc[2]);
            acc[3] = fmaf(xv[3], w3[j], acc[3]);
        }
    }
    f4 o;
#pragma unroll
    for (int c = 0; c < 4; c++) o[c] = silu_f(acc[c]);
    *(f4*)(xc + (size_t)t * 512 + e4) = o;
}

// ---------------------------------------------------------------------------
// Selective scan + skip + gate, 2-way state split (8 states/thread),
// depth-4 named-slot prefetch.  L % 4 == 0 (96, 32).
// ---------------------------------------------------------------------------
__global__ __launch_bounds__(256, 4)
void scan_gate8(float* __restrict__ dty,
                const float* __restrict__ xc,
                const float* __restrict__ xz,
                const float* __restrict__ dbl,
                const float* __restrict__ A_log,
                const float* __restrict__ Dvec,
                int L)
{
    int bn = blockIdx.x >> 2;
    int e  = ((blockIdx.x & 3) << 7) + (threadIdx.x >> 1);
    int sh = (threadIdx.x & 1) << 3;       // state half: 0 or 8

    float Ae[8], h[8];
#pragma unroll
    for (int s = 0; s < 8; s++) {
        Ae[s] = -__expf(A_log[e * D_STATE + sh + s]);
        h[s]  = 0.0f;
    }
    const float De = Dvec[e];

    const int base = bn * L;
    const int last = base + L - 1;

#define LOADS(tk, dt_, u_, Ba_, Bb_, Ca_, Cb_, z_)                       \
    dt_ = dty[(size_t)(tk) * 512 + e];                                   \
    u_  = xc [(size_t)(tk) * 512 + e];                                   \
    Ba_ = *(const f4*)(dbl + (size_t)(tk) * 48 + 16 + sh);               \
    Bb_ = *(const f4*)(dbl + (size_t)(tk) * 48 + 20 + sh);               \
    Ca_ = *(const f4*)(dbl + (size_t)(tk) * 48 + 32 + sh);               \
    Cb_ = *(const f4*)(dbl + (size_t)(tk) * 48 + 36 + sh);               \
    z_  = xz [(size_t)(tk) * 1024 + 512 + e];

#define COMPUTE(tk, dt_, u_, Ba_, Bb_, Ca_, Cb_, z_)                     \
    {                                                                    \
        float y = 0.0f;                                                  \
        float du = (dt_) * (u_);                                         \
        _Pragma("unroll")                                                \
        for (int s = 0; s < 4; s++) {                                    \
            float dA = __expf((dt_) * Ae[s]);                            \
            h[s] = fmaf(dA, h[s], du * (Ba_)[s]);                        \
            y    = fmaf(h[s], (Ca_)[s], y);                              \
        }                                                                \
        _Pragma("unroll")                                                \
        for (int s = 0; s < 4; s++) {                                    \
            float dA = __expf((dt_) * Ae[4 + s]);                        \
            h[4 + s] = fmaf(dA, h[4 + s], du * (Bb_)[s]);                \
            y        = fmaf(h[4 + s], (Cb_)[s], y);                      \
        }                                                                \
        y += __shfl_xor(y, 1);                                           \
        if (sh == 0)                                                     \
            dty[(size_t)(tk) * 512 + e] = (y + (u_) * De) * silu_f(z_);  \
    }

#define REFILL(slot_tk, dt_, u_, Ba_, Bb_, Ca_, Cb_, z_)                 \
    {                                                                    \
        int tp = (slot_tk) > last ? last : (slot_tk);                    \
        LOADS(tp, dt_, u_, Ba_, Bb_, Ca_, Cb_, z_);                      \
    }

    float dt0, u0, z0, dt1, u1, z1, dt2, u2, z2, dt3, u3, z3;
    f4 Ba0, Bb0, Ca0, Cb0, Ba1, Bb1, Ca1, Cb1;
    f4 Ba2, Bb2, Ca2, Cb2, Ba3, Bb3, Ca3, Cb3;
    LOADS(base,     dt0, u0, Ba0, Bb0, Ca0, Cb0, z0);
    LOADS(base + 1, dt1, u1, Ba1, Bb1, Ca1, Cb1, z1);
    LOADS(base + 2, dt2, u2, Ba2, Bb2, Ca2, Cb2, z2);
    LOADS(base + 3, dt3, u3, Ba3, Bb3, Ca3, Cb3, z3);

    for (int l = 0; l < L; l += 4) {
        int tk = base + l;
        COMPUTE(tk,     dt0, u0, Ba0, Bb0, Ca0, Cb0, z0);
        REFILL(tk + 4,  dt0, u0, Ba0, Bb0, Ca0, Cb0, z0);
        COMPUTE(tk + 1, dt1, u1, Ba1, Bb1, Ca1, Cb1, z1);
        REFILL(tk + 5,  dt1, u1, Ba1, Bb1, Ca1, Cb1, z1);
        COMPUTE(tk + 2, dt2, u2, Ba2, Bb2, Ca2, Cb2, z2);
        REFILL(tk + 6,  dt2, u2, Ba2, Bb2, Ca2, Cb2, z2);
        COMPUTE(tk + 3, dt3, u3, Ba3, Bb3, Ca3, Cb3, z3);
        REFILL(tk + 7,  dt3, u3, Ba3, Bb3, Ca3, Cb3, z3);
    }
#undef LOADS
#undef COMPUTE
#undef REFILL
}

// ---------------------------------------------------------------------------
// One mamba stage (weights pre-transposed to k-major).
// ---------------------------------------------------------------------------
template<int OUTMODE>
static void run_stage(const float* xin,
                      const float* in_wT, const float* conv_w, const float* conv_b,
                      const float* xproj_w, const float* dt_w, const float* dt_b,
                      const float* A_log, const float* Dvec, const float* out_wT,
                      float* xz, float* xc, float* dbl, float* dty, float* outp,
                      int Bn, int L, hipStream_t stream)
{
    const int M = TOKENS;
    // in_proj: [M,1024] = x[M,256] * in_w^T   (BN=128, BK=8, grid 384x8)
    gemm_v9<256, 128, 8, 0><<<dim3(M / 32, 1024 / 128), 256, 0, stream>>>(xin, in_wT, xz, 1024);
    // conv + silu (vectorized x4)
    conv_silu<<<dim3((M * 128) / 256), 256, 0, stream>>>(xz, conv_w, conv_b, xc, L);
    // fused x_proj + dt_proj (384 blocks)
    xproj_dt<<<dim3(M / 32), 256, 0, stream>>>(xc, xproj_w, dt_w, dt_b, dbl, dty, M);
    // scan + skip + gate (state-split 2x, depth-4 prefetch)
    scan_gate8<<<dim3(Bn * 4), 256, 0, stream>>>(dty, xc, xz, dbl, A_log, Dvec, L);
    // out_proj with fused layout transpose (BN=128, BK=8, grid 384x2)
    gemm_v9<512, 128, 8, OUTMODE><<<dim3(M / 32, 256 / 128), 256, 0, stream>>>(dty, out_wT, outp, 256);
}

extern "C" void kernel_launch(void* const* d_in, const int* in_sizes, int n_in,
                              void* d_out, int out_size, void* d_ws, size_t ws_size,
                              hipStream_t stream)
{
    const float* x = (const float*)d_in[0];
    const float* t_in_w    = (const float*)d_in[1];
    const float* t_conv_w  = (const float*)d_in[2];
    const float* t_conv_b  = (const float*)d_in[3];
    const float* t_xproj_w = (const float*)d_in[4];
    const float* t_dt_w    = (const float*)d_in[5];
    const float* t_dt_b    = (const float*)d_in[6];
    const float* t_A_log   = (const float*)d_in[7];
    const float* t_D       = (const float*)d_in[8];
    const float* t_out_w   = (const float*)d_in[9];
    const float* d_in_w    = (const float*)d_in[10];
    const float* d_conv_w  = (const float*)d_in[11];
    const float* d_conv_b  = (const float*)d_in[12];
    const float* d_xproj_w = (const float*)d_in[13];
    const float* d_dt_w    = (const float*)d_in[14];
    const float* d_dt_b    = (const float*)d_in[15];
    const float* d_A_log   = (const float*)d_in[16];
    const float* d_D       = (const float*)d_in[17];
    const float* d_out_w   = (const float*)d_in[18];

    float* ws  = (float*)d_ws;
    float* xz  = ws;
    float* xc  = xz  + (size_t)TOKENS * 1024;
    float* dbl = xc  + (size_t)TOKENS * 512;
    float* dty = dbl + (size_t)TOKENS * 48;
    float* xt  = dty + (size_t)TOKENS * 512;
    float* t_in_wT  = xt + (size_t)TOKENS * 256;     // [256][1024]
    float* t_out_wT = t_in_wT  + 262144;             // [512][256]
    float* d_in_wT  = t_out_wT + 131072;             // [256][1024]
    float* d_out_wT = d_in_wT  + 262144;             // [512][256]
    const size_t need_bytes =
        ((size_t)TOKENS * (1024 + 512 + 48 + 512 + 256) + 2 * (262144 + 131072)) * 4;
    if (ws_size < need_bytes) return;

    // pre-transpose the four big weights to k-major
    transpose_w<<<dim3(256 / 32, 1024 / 32), 256, 0, stream>>>(t_in_w,  t_in_wT,  1024, 256);
    transpose_w<<<dim3(512 / 32,  256 / 32), 256, 0, stream>>>(t_out_w, t_out_wT,  256, 512);
    transpose_w<<<dim3(256 / 32, 1024 / 32), 256, 0, stream>>>(d_in_w,  d_in_wT,  1024, 256);
    transpose_w<<<dim3(512 / 32,  256 / 32), 256, 0, stream>>>(d_out_w, d_out_wT,  256, 512);

    // stage 1: time scan, Bn = 128, L = 96
    run_stage<2>(x, t_in_wT, t_conv_w, t_conv_b, t_xproj_w, t_dt_w, t_dt_b,
                 t_A_log, t_D, t_out_wT, xz, xc, dbl, dty, xt,
                 NB * NVAR, SEG, stream);
    // stage 2: dimension scan, Bn = 384, L = 32
    run_stage<3>(xt, d_in_wT, d_conv_w, d_conv_b, d_xproj_w, d_dt_w, d_dt_b,
                 d_A_log, d_D, d_out_wT, xz, xc, dbl, dty, (float*)d_out,
                 NB * SEG, NVAR, stream);
}

// Round 18
// 463.855 us; speedup vs baseline: 1.0379x; 1.0379x over previous
//
#include <hip/hip_runtime.h>
#include <hip/hip_bf16.h>
#include <math.h>

#define D_MODEL 256
#define D_STATE 16
#define D_INNER 512
#define DT_RANK 16
#define NB 4
#define NVAR 32
#define SEG 96
#define TOKENS (NB*NVAR*SEG)   /* 12288 */

typedef float f4 __attribute__((ext_vector_type(4)));

__device__ __forceinline__ float silu_f(float x) { return x / (1.0f + __expf(-x)); }

// ---------------------------------------------------------------------------
// WT[k][n] = W[n][k].  W: [N][K].  grid (K/32, N/32), block 256.
// ---------------------------------------------------------------------------
__global__ __launch_bounds__(256)
void transpose_w(const float* __restrict__ W, float* __restrict__ WT, int N, int K)
{
    __shared__ float t[32][33];
    const int k0 = blockIdx.x * 32, n0 = blockIdx.y * 32;
    const int tx = threadIdx.x & 31, ty = threadIdx.x >> 5;
#pragma unroll
    for (int i = 0; i < 32; i += 8)
        t[ty + i][tx] = W[(size_t)(n0 + ty + i) * K + k0 + tx];
    __syncthreads();
#pragma unroll
    for (int i = 0; i < 32; i += 8)
        WT[(size_t)(k0 + ty + i) * N + n0 + tx] = t[tx][ty + i];
}

// ---------------------------------------------------------------------------
// NT GEMM v10 (= round-15 v6 + BM template): C[m,n] = sum_k A[m,k]*WT[k][n].
// 256 thr = 4 waves; wave owns WR=BM/4 rows (A wave-uniform -> s_load/SGPR,
// v_fma reads the SGPR operand directly -> VGPR stays low).
// W: coalesced global_load_lds DMA into linear LDS [BK][BN], double-buffered,
// one barrier per K-tile (__syncthreads; pipelining variants v7/v8/v9 all
// regressed -- r8/r12/r16/r17).  BM=64 doubles per-wave FMA per W-element
// (16xCPL per k) to amortize the lgkm stalls that capped VALUBusy at ~57%.
// MODE 0 plain; 2: rows (b,v,s)->(b,s,v); 3: inverse.
// ---------------------------------------------------------------------------
template<int K, int BM, int BN, int BK, int MODE>
__global__ __launch_bounds__(256, 4)
void gemm_v10(const float* __restrict__ A, const float* __restrict__ WT,
              float* __restrict__ C, int N)
{
    constexpr int NT  = K / BK;
    constexpr int WR  = BM / 4;                  // rows per wave (8 or 16)
    constexpr int CPL = BN / 64;                 // 4 (BN=256) or 2 (BN=128)
    constexpr int KRD = 1024 / (BN * 4);         // k-rows per 1KB DMA: 1 or 2
    constexpr int J   = BK / (KRD * 4);          // DMA instrs per wave
    typedef float cvec __attribute__((ext_vector_type(CPL)));
    __shared__ float wlds[2 * BK * BN];

    const int tid  = threadIdx.x;
    const int lane = tid & 63;
    const int wid  = __builtin_amdgcn_readfirstlane(tid >> 6);
    const int m0 = blockIdx.x * BM;
    const int n0 = blockIdx.y * BN;

    // wave-uniform A row pointers -> s_load fragments (scalar pipe)
    const float* Ar[WR];
#pragma unroll
    for (int r = 0; r < WR; r++)
        Ar[r] = A + (size_t)(m0 + wid * WR + r) * K;

    // coalesced DMA: each instr stages KRD k-rows (1 KB) of WT
    auto stage = [&](int dbuf, int k0) {
#pragma unroll
        for (int j = 0; j < J; j++) {
            int kb   = (wid * J + j) * KRD;
            int krow = kb + ((KRD == 2) ? (lane >> 5) : 0);
            int nofs = ((KRD == 2) ? (lane & 31) : lane) * 4;
            int dstw = __builtin_amdgcn_readfirstlane(dbuf * (BK * BN) + kb * BN);
            __builtin_amdgcn_global_load_lds(
                (const __attribute__((address_space(1))) void*)
                    (WT + (size_t)(k0 + krow) * N + n0 + nofs),
                (__attribute__((address_space(3))) void*)(wlds + dstw), 16, 0, 0);
        }
    };

    float acc[WR][CPL];
#pragma unroll
    for (int r = 0; r < WR; r++)
#pragma unroll
        for (int g = 0; g < CPL; g++) acc[r][g] = 0.0f;

    stage(0, 0);
    __syncthreads();                             // tile 0 resident

    for (int t = 0; t < NT; t++) {
        const int k0 = t * BK;
        if (t + 1 < NT) stage((t + 1) & 1, k0 + BK);   // issue-early
        const float* Wb = wlds + (t & 1) * (BK * BN);
#pragma unroll
        for (int q = 0; q < BK / 4; q++) {
            f4 a4[WR];
#pragma unroll
            for (int r = 0; r < WR; r++)         // uniform -> s_load_dwordx4
                a4[r] = *(const f4*)(Ar[r] + k0 + 4 * q);
#pragma unroll
            for (int e = 0; e < 4; e++) {
                cvec wv = *(const cvec*)(Wb + (4 * q + e) * BN + CPL * lane);
#pragma unroll
                for (int r = 0; r < WR; r++)
#pragma unroll
                    for (int g = 0; g < CPL; g++)
                        acc[r][g] = fmaf(a4[r][e], wv[g], acc[r][g]);
            }
        }
        __syncthreads();                         // drains DMA + guards dbuf
    }

#pragma unroll
    for (int r = 0; r < WR; r++) {
        int m = m0 + wid * WR + r;
        int orow = m;
        if (MODE == 2) {                         // (b*32+v)*96+s -> (b*96+s)*32+v
            int b = m / 3072, rr = m % 3072;
            int v = rr / 96, s = rr % 96;
            orow = (b * 96 + s) * 32 + v;
        } else if (MODE == 3) {                  // (b*96+s)*32+v -> (b*32+v)*96+s
            int b = m / 3072, rr = m % 3072;
            int s = rr / 32, v = rr % 32;
            orow = (b * 32 + v) * 96 + s;
        }
        cvec v;
#pragma unroll
        for (int g = 0; g < CPL; g++) v[g] = acc[r][g];
        *(cvec*)(C + (size_t)orow * N + n0 + CPL * lane) = v;
    }
}

// ---------------------------------------------------------------------------
// Fused x_proj + dt_proj: one block owns 32 full rows.
// ---------------------------------------------------------------------------
__global__ __launch_bounds__(256)
void xproj_dt(const float* __restrict__ xc,
              const float* __restrict__ xpw,    // [48][512]
              const float* __restrict__ dtw,    // [512][16]
              const float* __restrict__ dtb,    // [512]
              float* __restrict__ dbl,          // [M][48]
              float* __restrict__ dty,          // [M][512]
              int M)
{
    constexpr int BM = 32, BN = 64, BK = 32, TM = 2, TN = 4;
    __shared__ float As[BK][BM + 4];
    __shared__ float Ws[BK][BN + 4];
    __shared__ float dbl_s[BM][52];

    const int tid = threadIdx.x;
    const int tx  = tid % (BN / TN);
    const int ty  = tid / (BN / TN);
    const int m0  = blockIdx.x * BM;

    float acc[TM][TN];
#pragma unroll
    for (int i = 0; i < TM; i++)
#pragma unroll
        for (int j = 0; j < TN; j++) acc[i][j] = 0.0f;

    constexpr int AF4 = (BM * BK) / 1024;
    constexpr int WF4 = (BN * BK) / 1024;
    constexpr int F4R = BK / 4;

    for (int k0 = 0; k0 < 512; k0 += BK) {
#pragma unroll
        for (int c = 0; c < AF4; c++) {
            int idx = tid + c * 256;
            int row = idx / F4R;
            int kc  = (idx % F4R) * 4;
            float4 v = *(const float4*)(xc + (size_t)(m0 + row) * 512 + k0 + kc);
            As[kc + 0][row] = v.x;
            As[kc + 1][row] = v.y;
            As[kc + 2][row] = v.z;
            As[kc + 3][row] = v.w;
        }
#pragma unroll
        for (int c = 0; c < WF4; c++) {
            int idx = tid + c * 256;
            int row = idx / F4R;
            int kc  = (idx % F4R) * 4;
            float4 v;
            if (row < 48) v = *(const float4*)(xpw + (size_t)row * 512 + k0 + kc);
            else          v = make_float4(0.f, 0.f, 0.f, 0.f);
            Ws[kc + 0][row] = v.x;
            Ws[kc + 1][row] = v.y;
            Ws[kc + 2][row] = v.z;
            Ws[kc + 3][row] = v.w;
        }
        __syncthreads();

#pragma unroll
        for (int kk = 0; kk < BK; kk++) {
            float a[TM], w[TN];
#pragma unroll
            for (int i = 0; i < TM; i++) a[i] = As[kk][ty * TM + i];
#pragma unroll
            for (int j = 0; j < TN; j++) w[j] = Ws[kk][tx * TN + j];
#pragma unroll
            for (int i = 0; i < TM; i++)
#pragma unroll
                for (int j = 0; j < TN; j++)
                    acc[i][j] = fmaf(a[i], w[j], acc[i][j]);
        }
        __syncthreads();
    }

#pragma unroll
    for (int i = 0; i < TM; i++) {
        int mr = ty * TM + i;
#pragma unroll
        for (int j = 0; j < TN; j++) {
            int n = tx * TN + j;
            if (n < 48) {
                dbl[(size_t)(m0 + mr) * 48 + n] = acc[i][j];
                dbl_s[mr][n] = acc[i][j];
            }
        }
    }
    __syncthreads();

    f4 wA[4], wB[4];
#pragma unroll
    for (int c = 0; c < 4; c++) {
        wA[c] = *(const f4*)(dtw + (size_t)tid * 16 + 4 * c);
        wB[c] = *(const f4*)(dtw + (size_t)(tid + 256) * 16 + 4 * c);
    }
    const float bA = dtb[tid], bB = dtb[tid + 256];
#pragma unroll 4
    for (int r = 0; r < BM; r++) {
        f4 d[4];
#pragma unroll
        for (int c = 0; c < 4; c++) d[c] = *(const f4*)(&dbl_s[r][4 * c]);
        float vA = bA, vB = bB;
#pragma unroll
        for (int c = 0; c < 4; c++)
#pragma unroll
            for (int e = 0; e < 4; e++) {
                vA = fmaf(d[c][e], wA[c][e], vA);
                vB = fmaf(d[c][e], wB[c][e], vB);
            }
        vA = (vA > 20.0f) ? vA : log1pf(__expf(vA));
        vB = (vB > 20.0f) ? vB : log1pf(__expf(vB));
        dty[(size_t)(m0 + r) * 512 + tid]       = vA;
        dty[(size_t)(m0 + r) * 512 + tid + 256] = vB;
    }
}

// ---------------------------------------------------------------------------
// Depthwise causal conv (width 4) + bias + SiLU, vectorized x4 channels.
// ---------------------------------------------------------------------------
__global__ __launch_bounds__(256)
void conv_silu(const float* __restrict__ xz, const float* __restrict__ cw,
               const float* __restrict__ cb, float* __restrict__ xc, int L)
{
    int i  = blockIdx.x * 256 + threadIdx.x;     // one per 4 channels
    int e4 = (i & 127) << 2;
    int t  = i >> 7;
    int l  = t % L;
    const f4 w0 = *(const f4*)(cw + e4 * 4);
    const f4 w1 = *(const f4*)(cw + e4 * 4 + 4);
    const f4 w2 = *(const f4*)(cw + e4 * 4 + 8);
    const f4 w3 = *(const f4*)(cw + e4 * 4 + 12);
    f4 acc = *(const f4*)(cb + e4);
#pragma unroll
    for (int j = 0; j < 4; j++) {
        int li = l - 3 + j;
        if (li >= 0) {
            f4 xv = *(const f4*)(xz + (size_t)(t + li - l) * 1024 + e4);
            acc[0] = fmaf(xv[0], w0[j], acc[0]);
            acc[1] = fmaf(xv[1], w1[j], acc[1]);
            acc[2] = fmaf(xv[2], w2[j], acc[2]);
            acc[3] = fmaf(xv[3], w3[j], acc[3]);
        }
    }
    f4 o;
#pragma unroll
    for (int c = 0; c < 4; c++) o[c] = silu_f(acc[c]);
    *(f4*)(xc + (size_t)t * 512 + e4) = o;
}

// ---------------------------------------------------------------------------
// Selective scan + skip + gate, 2-way state split (8 states/thread),
// depth-4 named-slot prefetch.  L % 4 == 0 (96, 32).
// ---------------------------------------------------------------------------
__global__ __launch_bounds__(256, 4)
void scan_gate8(float* __restrict__ dty,
                const float* __restrict__ xc,
                const float* __restrict__ xz,
                const float* __restrict__ dbl,
                const float* __restrict__ A_log,
                const float* __restrict__ Dvec,
                int L)
{
    int bn = blockIdx.x >> 2;
    int e  = ((blockIdx.x & 3) << 7) + (threadIdx.x >> 1);
    int sh = (threadIdx.x & 1) << 3;       // state half: 0 or 8

    float Ae[8], h[8];
#pragma unroll
    for (int s = 0; s < 8; s++) {
        Ae[s] = -__expf(A_log[e * D_STATE + sh + s]);
        h[s]  = 0.0f;
    }
    const float De = Dvec[e];

    const int base = bn * L;
    const int last = base + L - 1;

#define LOADS(tk, dt_, u_, Ba_, Bb_, Ca_, Cb_, z_)                       \
    dt_ = dty[(size_t)(tk) * 512 + e];                                   \
    u_  = xc [(size_t)(tk) * 512 + e];                                   \
    Ba_ = *(const f4*)(dbl + (size_t)(tk) * 48 + 16 + sh);               \
    Bb_ = *(const f4*)(dbl + (size_t)(tk) * 48 + 20 + sh);               \
    Ca_ = *(const f4*)(dbl + (size_t)(tk) * 48 + 32 + sh);               \
    Cb_ = *(const f4*)(dbl + (size_t)(tk) * 48 + 36 + sh);               \
    z_  = xz [(size_t)(tk) * 1024 + 512 + e];

#define COMPUTE(tk, dt_, u_, Ba_, Bb_, Ca_, Cb_, z_)                     \
    {                                                                    \
        float y = 0.0f;                                                  \
        float du = (dt_) * (u_);                                         \
        _Pragma("unroll")                                                \
        for (int s = 0; s < 4; s++) {                                    \
            float dA = __expf((dt_) * Ae[s]);                            \
            h[s] = fmaf(dA, h[s], du * (Ba_)[s]);                        \
            y    = fmaf(h[s], (Ca_)[s], y);                              \
        }                                                                \
        _Pragma("unroll")                                                \
        for (int s = 0; s < 4; s++) {                                    \
            float dA = __expf((dt_) * Ae[4 + s]);                        \
            h[4 + s] = fmaf(dA, h[4 + s], du * (Bb_)[s]);                \
            y        = fmaf(h[4 + s], (Cb_)[s], y);                      \
        }                                                                \
        y += __shfl_xor(y, 1);                                           \
        if (sh == 0)                                                     \
            dty[(size_t)(tk) * 512 + e] = (y + (u_) * De) * silu_f(z_);  \
    }

#define REFILL(slot_tk, dt_, u_, Ba_, Bb_, Ca_, Cb_, z_)                 \
    {                                                                    \
        int tp = (slot_tk) > last ? last : (slot_tk);                    \
        LOADS(tp, dt_, u_, Ba_, Bb_, Ca_, Cb_, z_);                      \
    }

    float dt0, u0, z0, dt1, u1, z1, dt2, u2, z2, dt3, u3, z3;
    f4 Ba0, Bb0, Ca0, Cb0, Ba1, Bb1, Ca1, Cb1;
    f4 Ba2, Bb2, Ca2, Cb2, Ba3, Bb3, Ca3, Cb3;
    LOADS(base,     dt0, u0, Ba0, Bb0, Ca0, Cb0, z0);
    LOADS(base + 1, dt1, u1, Ba1, Bb1, Ca1, Cb1, z1);
    LOADS(base + 2, dt2, u2, Ba2, Bb2, Ca2, Cb2, z2);
    LOADS(base + 3, dt3, u3, Ba3, Bb3, Ca3, Cb3, z3);

    for (int l = 0; l < L; l += 4) {
        int tk = base + l;
        COMPUTE(tk,     dt0, u0, Ba0, Bb0, Ca0, Cb0, z0);
        REFILL(tk + 4,  dt0, u0, Ba0, Bb0, Ca0, Cb0, z0);
        COMPUTE(tk + 1, dt1, u1, Ba1, Bb1, Ca1, Cb1, z1);
        REFILL(tk + 5,  dt1, u1, Ba1, Bb1, Ca1, Cb1, z1);
        COMPUTE(tk + 2, dt2, u2, Ba2, Bb2, Ca2, Cb2, z2);
        REFILL(tk + 6,  dt2, u2, Ba2, Bb2, Ca2, Cb2, z2);
        COMPUTE(tk + 3, dt3, u3, Ba3, Bb3, Ca3, Cb3, z3);
        REFILL(tk + 7,  dt3, u3, Ba3, Bb3, Ca3, Cb3, z3);
    }
#undef LOADS
#undef COMPUTE
#undef REFILL
}

// ---------------------------------------------------------------------------
// One mamba stage (weights pre-transposed to k-major).
// ---------------------------------------------------------------------------
template<int OUTMODE>
static void run_stage(const float* xin,
                      const float* in_wT, const float* conv_w, const float* conv_b,
                      const float* xproj_w, const float* dt_w, const float* dt_b,
                      const float* A_log, const float* Dvec, const float* out_wT,
                      float* xz, float* xc, float* dbl, float* dty, float* outp,
                      int Bn, int L, hipStream_t stream)
{
    const int M = TOKENS;
    // in_proj: [M,1024] = x[M,256] * in_w^T   (BM=64, BN=256, BK=8, grid 192x4)
    gemm_v10<256, 64, 256, 8, 0><<<dim3(M / 64, 1024 / 256), 256, 0, stream>>>(xin, in_wT, xz, 1024);
    // conv + silu (vectorized x4)
    conv_silu<<<dim3((M * 128) / 256), 256, 0, stream>>>(xz, conv_w, conv_b, xc, L);
    // fused x_proj + dt_proj (384 blocks)
    xproj_dt<<<dim3(M / 32), 256, 0, stream>>>(xc, xproj_w, dt_w, dt_b, dbl, dty, M);
    // scan + skip + gate (state-split 2x, depth-4 prefetch)
    scan_gate8<<<dim3(Bn * 4), 256, 0, stream>>>(dty, xc, xz, dbl, A_log, Dvec, L);
    // out_proj with fused layout transpose (BM=32, BN=128, BK=32, grid 384x2)
    gemm_v10<512, 32, 128, 32, OUTMODE><<<dim3(M / 32, 256 / 128), 256, 0, stream>>>(dty, out_wT, outp, 256);
}

extern "C" void kernel_launch(void* const* d_in, const int* in_sizes, int n_in,
                              void* d_out, int out_size, void* d_ws, size_t ws_size,
                              hipStream_t stream)
{
    const float* x = (const float*)d_in[0];
    const float* t_in_w    = (const float*)d_in[1];
    const float* t_conv_w  = (const float*)d_in[2];
    const float* t_conv_b  = (const float*)d_in[3];
    const float* t_xproj_w = (const float*)d_in[4];
    const float* t_dt_w    = (const float*)d_in[5];
    const float* t_dt_b    = (const float*)d_in[6];
    const float* t_A_log   = (const float*)d_in[7];
    const float* t_D       = (const float*)d_in[8];
    const float* t_out_w   = (const float*)d_in[9];
    const float* d_in_w    = (const float*)d_in[10];
    const float* d_conv_w  = (const float*)d_in[11];
    const float* d_conv_b  = (const float*)d_in[12];
    const float* d_xproj_w = (const float*)d_in[13];
    const float* d_dt_w    = (const float*)d_in[14];
    const float* d_dt_b    = (const float*)d_in[15];
    const float* d_A_log   = (const float*)d_in[16];
    const float* d_D       = (const float*)d_in[17];
    const float* d_out_w   = (const float*)d_in[18];

    float* ws  = (float*)d_ws;
    float* xz  = ws;
    float* xc  = xz  + (size_t)TOKENS * 1024;
    float* dbl = xc  + (size_t)TOKENS * 512;
    float* dty = dbl + (size_t)TOKENS * 48;
    float* xt  = dty + (size_t)TOKENS * 512;
    float* t_in_wT  = xt + (size_t)TOKENS * 256;     // [256][1024]
    float* t_out_wT = t_in_wT  + 262144;             // [512][256]
    float* d_in_wT  = t_out_wT + 131072;             // [256][1024]
    float* d_out_wT = d_in_wT  + 262144;             // [512][256]
    const size_t need_bytes =
        ((size_t)TOKENS * (1024 + 512 + 48 + 512 + 256) + 2 * (262144 + 131072)) * 4;
    if (ws_size < need_bytes) return;

    // pre-transpose the four big weights to k-major
    transpose_w<<<dim3(256 / 32, 1024 / 32), 256, 0, stream>>>(t_in_w,  t_in_wT,  1024, 256);
    transpose_w<<<dim3(512 / 32,  256 / 32), 256, 0, stream>>>(t_out_w, t_out_wT,  256, 512);
    transpose_w<<<dim3(256 / 32, 1024 / 32), 256, 0, stream>>>(d_in_w,  d_in_wT,  1024, 256);
    transpose_w<<<dim3(512 / 32,  256 / 32), 256, 0, stream>>>(d_out_w, d_out_wT,  256, 512);

    // stage 1: time scan, Bn = 128, L = 96
    run_stage<2>(x, t_in_wT, t_conv_w, t_conv_b, t_xproj_w, t_dt_w, t_dt_b,
                 t_A_log, t_D, t_out_wT, xz, xc, dbl, dty, xt,
                 NB * NVAR, SEG, stream);
    // stage 2: dimension scan, Bn = 384, L = 32
    run_stage<3>(xt, d_in_wT, d_conv_w, d_conv_b, d_xproj_w, d_dt_w, d_dt_b,
                 d_A_log, d_D, d_out_wT, xz, xc, dbl, dty, (float*)d_out,
                 NB * SEG, NVAR, stream);
}

// Round 19
// 456.407 us; speedup vs baseline: 1.0548x; 1.0163x over previous
//
#include <hip/hip_runtime.h>
#include <hip/hip_bf16.h>
#include <math.h>

#define D_MODEL 256
#define D_STATE 16
#define D_INNER 512
#define DT_RANK 16
#define NB 4
#define NVAR 32
#define SEG 96
#define TOKENS (NB*NVAR*SEG)   /* 12288 */

typedef float f4 __attribute__((ext_vector_type(4)));

__device__ __forceinline__ float silu_f(float x) { return x / (1.0f + __expf(-x)); }

// ---------------------------------------------------------------------------
// Batched transpose: z in {0,1} picks (W0->WT0) or (W1->WT1).  W: [N][K].
// grid (K/32, N/32, 2), block 256.
// ---------------------------------------------------------------------------
__global__ __launch_bounds__(256)
void transpose_w2(const float* __restrict__ W0, float* __restrict__ WT0,
                  const float* __restrict__ W1, float* __restrict__ WT1,
                  int N, int K)
{
    const float* W  = blockIdx.z ? W1  : W0;
    float*       WT = blockIdx.z ? WT1 : WT0;
    __shared__ float t[32][33];
    const int k0 = blockIdx.x * 32, n0 = blockIdx.y * 32;
    const int tx = threadIdx.x & 31, ty = threadIdx.x >> 5;
#pragma unroll
    for (int i = 0; i < 32; i += 8)
        t[ty + i][tx] = W[(size_t)(n0 + ty + i) * K + k0 + tx];
    __syncthreads();
#pragma unroll
    for (int i = 0; i < 32; i += 8)
        WT[(size_t)(k0 + ty + i) * N + n0 + tx] = t[tx][ty + i];
}

// ---------------------------------------------------------------------------
// NT GEMM v6 (round-15 proven config): C[m,n] = sum_k A[m,k]*WT[k][n].
// 256 thr = 4 waves; BM=32 (wave owns 8 rows; A wave-uniform -> s_load).
// W: coalesced global_load_lds DMA into linear LDS [BK][BN], double-buffered,
// one barrier per K-tile.  This structure's plateau is ~53% of fp32 peak
// (77us for in_proj) -- verified optimal over BK{8,16,32}, BN{128,256},
// BM{32,64}, A-path{s_load,VMEM,LDS}, pipelining{dbuf,counted-vmcnt}.
// MODE 0 plain; 2: rows (b,v,s)->(b,s,v); 3: inverse.
// ---------------------------------------------------------------------------
template<int K, int BN, int BK, int MODE>
__global__ __launch_bounds__(256, 4)
void gemm_v6(const float* __restrict__ A, const float* __restrict__ WT,
             float* __restrict__ C, int N)
{
    constexpr int NT  = K / BK;
    constexpr int CPL = BN / 64;                 // 4 (BN=256) or 2 (BN=128)
    constexpr int KRD = 1024 / (BN * 4);         // k-rows per 1KB DMA: 1 or 2
    constexpr int J   = BK / (KRD * 4);          // DMA instrs per wave
    typedef float cvec __attribute__((ext_vector_type(CPL)));
    __shared__ float wlds[2 * BK * BN];

    const int tid  = threadIdx.x;
    const int lane = tid & 63;
    const int wid  = __builtin_amdgcn_readfirstlane(tid >> 6);
    const int m0 = blockIdx.x * 32;
    const int n0 = blockIdx.y * BN;

    const float* Ar[8];
#pragma unroll
    for (int r = 0; r < 8; r++)
        Ar[r] = A + (size_t)(m0 + wid * 8 + r) * K;

    auto stage = [&](int dbuf, int k0) {
#pragma unroll
        for (int j = 0; j < J; j++) {
            int kb   = (wid * J + j) * KRD;
            int krow = kb + ((KRD == 2) ? (lane >> 5) : 0);
            int nofs = ((KRD == 2) ? (lane & 31) : lane) * 4;
            int dstw = __builtin_amdgcn_readfirstlane(dbuf * (BK * BN) + kb * BN);
            __builtin_amdgcn_global_load_lds(
                (const __attribute__((address_space(1))) void*)
                    (WT + (size_t)(k0 + krow) * N + n0 + nofs),
                (__attribute__((address_space(3))) void*)(wlds + dstw), 16, 0, 0);
        }
    };

    float acc[8][CPL];
#pragma unroll
    for (int r = 0; r < 8; r++)
#pragma unroll
        for (int g = 0; g < CPL; g++) acc[r][g] = 0.0f;

    stage(0, 0);
    __syncthreads();

    for (int t = 0; t < NT; t++) {
        const int k0 = t * BK;
        if (t + 1 < NT) stage((t + 1) & 1, k0 + BK);
        const float* Wb = wlds + (t & 1) * (BK * BN);
#pragma unroll
        for (int q = 0; q < BK / 4; q++) {
            f4 a4[8];
#pragma unroll
            for (int r = 0; r < 8; r++)
                a4[r] = *(const f4*)(Ar[r] + k0 + 4 * q);
#pragma unroll
            for (int e = 0; e < 4; e++) {
                cvec wv = *(const cvec*)(Wb + (4 * q + e) * BN + CPL * lane);
#pragma unroll
                for (int r = 0; r < 8; r++)
#pragma unroll
                    for (int g = 0; g < CPL; g++)
                        acc[r][g] = fmaf(a4[r][e], wv[g], acc[r][g]);
            }
        }
        __syncthreads();
    }

#pragma unroll
    for (int r = 0; r < 8; r++) {
        int m = m0 + wid * 8 + r;
        int orow = m;
        if (MODE == 2) {                         // (b*32+v)*96+s -> (b*96+s)*32+v
            int b = m / 3072, rr = m % 3072;
            int v = rr / 96, s = rr % 96;
            orow = (b * 96 + s) * 32 + v;
        } else if (MODE == 3) {                  // (b*96+s)*32+v -> (b*32+v)*96+s
            int b = m / 3072, rr = m % 3072;
            int s = rr / 32, v = rr % 32;
            orow = (b * 32 + v) * 96 + s;
        }
        cvec v;
#pragma unroll
        for (int g = 0; g < CPL; g++) v[g] = acc[r][g];
        *(cvec*)(C + (size_t)orow * N + n0 + CPL * lane) = v;
    }
}

// ---------------------------------------------------------------------------
// Fused conv + x_proj + dt_proj: one block owns 32 full rows (one tile never
// crosses a sequence boundary: L in {96,32}, 32 | L).  A-staging computes
// xc = silu(causal_conv4(xz.xi) + cb) on the fly (rows m-3..m, zero-pad when
// (m0%L)+row < 3) -- the separate conv kernel and the xc buffer are gone.
// Phase 2: dty = softplus(dbl[:, :16] * dtw^T + dtb).
// ---------------------------------------------------------------------------
__global__ __launch_bounds__(256)
void xproj_dt_conv(const float* __restrict__ xz,   // [M][1024]
                   const float* __restrict__ cw,   // [512][4]
                   const float* __restrict__ cb,   // [512]
                   const float* __restrict__ xpw,  // [48][512]
                   const float* __restrict__ dtw,  // [512][16]
                   const float* __restrict__ dtb,  // [512]
                   float* __restrict__ dbl,        // [M][48]
                   float* __restrict__ dty,        // [M][512]
                   int M, int L)
{
    constexpr int BM = 32, BN = 64, BK = 32, TM = 2, TN = 4;
    __shared__ float As[BK][BM + 4];
    __shared__ float Ws[BK][BN + 4];
    __shared__ float dbl_s[BM][52];

    const int tid = threadIdx.x;
    const int tx  = tid % (BN / TN);
    const int ty  = tid / (BN / TN);
    const int m0  = blockIdx.x * BM;
    const int lmb = m0 % L;                      // seq-local index of row 0

    // staging role: row = tid>>3 (0..31), kc = (tid&7)*4
    const int s_row = tid >> 3;
    const int s_kc  = (tid & 7) << 2;
    const int s_m   = m0 + s_row;
    const int s_lm  = lmb + s_row;

    float acc[TM][TN];
#pragma unroll
    for (int i = 0; i < TM; i++)
#pragma unroll
        for (int j = 0; j < TN; j++) acc[i][j] = 0.0f;

    constexpr int WF4 = (BN * BK) / 1024;
    constexpr int F4R = BK / 4;

    for (int k0 = 0; k0 < 512; k0 += BK) {
        // --- fused conv staging of As: 4 xz rows, 4 taps, SiLU ---
        {
            const int col0 = k0 + s_kc;
            f4 xv[4];
#pragma unroll
            for (int j = 0; j < 4; j++) {
                if (s_lm - 3 + j >= 0)
                    xv[j] = *(const f4*)(xz + (size_t)(s_m - 3 + j) * 1024 + col0);
                else
                    xv[j] = (f4)0.0f;
            }
            f4 bv = *(const f4*)(cb + col0);
#pragma unroll
            for (int c = 0; c < 4; c++) {
                f4 w = *(const f4*)(cw + (size_t)(col0 + c) * 4);
                float v = bv[c];
#pragma unroll
                for (int j = 0; j < 4; j++)
                    v = fmaf(xv[j][c], w[j], v);
                As[s_kc + c][s_row] = silu_f(v);
            }
        }
        // --- W staging (xpw) ---
#pragma unroll
        for (int c = 0; c < WF4; c++) {
            int idx = tid + c * 256;
            int row = idx / F4R;
            int kc  = (idx % F4R) * 4;
            float4 v;
            if (row < 48) v = *(const float4*)(xpw + (size_t)row * 512 + k0 + kc);
            else          v = make_float4(0.f, 0.f, 0.f, 0.f);
            Ws[kc + 0][row] = v.x;
            Ws[kc + 1][row] = v.y;
            Ws[kc + 2][row] = v.z;
            Ws[kc + 3][row] = v.w;
        }
        __syncthreads();

#pragma unroll
        for (int kk = 0; kk < BK; kk++) {
            float a[TM], w[TN];
#pragma unroll
            for (int i = 0; i < TM; i++) a[i] = As[kk][ty * TM + i];
#pragma unroll
            for (int j = 0; j < TN; j++) w[j] = Ws[kk][tx * TN + j];
#pragma unroll
            for (int i = 0; i < TM; i++)
#pragma unroll
                for (int j = 0; j < TN; j++)
                    acc[i][j] = fmaf(a[i], w[j], acc[i][j]);
        }
        __syncthreads();
    }

#pragma unroll
    for (int i = 0; i < TM; i++) {
        int mr = ty * TM + i;
#pragma unroll
        for (int j = 0; j < TN; j++) {
            int n = tx * TN + j;
            if (n < 48) {
                dbl[(size_t)(m0 + mr) * 48 + n] = acc[i][j];
                dbl_s[mr][n] = acc[i][j];
            }
        }
    }
    __syncthreads();

    f4 wA[4], wB[4];
#pragma unroll
    for (int c = 0; c < 4; c++) {
        wA[c] = *(const f4*)(dtw + (size_t)tid * 16 + 4 * c);
        wB[c] = *(const f4*)(dtw + (size_t)(tid + 256) * 16 + 4 * c);
    }
    const float bA = dtb[tid], bB = dtb[tid + 256];
#pragma unroll 4
    for (int r = 0; r < BM; r++) {
        f4 d[4];
#pragma unroll
        for (int c = 0; c < 4; c++) d[c] = *(const f4*)(&dbl_s[r][4 * c]);
        float vA = bA, vB = bB;
#pragma unroll
        for (int c = 0; c < 4; c++)
#pragma unroll
            for (int e = 0; e < 4; e++) {
                vA = fmaf(d[c][e], wA[c][e], vA);
                vB = fmaf(d[c][e], wB[c][e], vB);
            }
        vA = (vA > 20.0f) ? vA : log1pf(__expf(vA));
        vB = (vB > 20.0f) ? vB : log1pf(__expf(vB));
        dty[(size_t)(m0 + r) * 512 + tid]       = vA;
        dty[(size_t)(m0 + r) * 512 + tid + 256] = vB;
    }
}

// ---------------------------------------------------------------------------
// Selective scan + skip + gate, 2-way state split (8 states/thread),
// depth-4 named-slot prefetch, CONV FUSED: u = silu(conv4(xi)) computed from
// a 3-register rolling window (sequential in l), replacing the xc load.
// L % 4 == 0 (96, 32).
// ---------------------------------------------------------------------------
__global__ __launch_bounds__(256, 4)
void scan_gate8c(float* __restrict__ dty,
                 const float* __restrict__ xz,
                 const float* __restrict__ dbl,
                 const float* __restrict__ cw,
                 const float* __restrict__ cb,
                 const float* __restrict__ A_log,
                 const float* __restrict__ Dvec,
                 int L)
{
    int bn = blockIdx.x >> 2;
    int e  = ((blockIdx.x & 3) << 7) + (threadIdx.x >> 1);
    int sh = (threadIdx.x & 1) << 3;       // state half: 0 or 8

    float Ae[8], h[8];
#pragma unroll
    for (int s = 0; s < 8; s++) {
        Ae[s] = -__expf(A_log[e * D_STATE + sh + s]);
        h[s]  = 0.0f;
    }
    const float De  = Dvec[e];
    const f4 cwe    = *(const f4*)(cw + (size_t)e * 4);
    const float cbe = cb[e];
    float w0 = 0.f, w1 = 0.f, w2 = 0.f;    // conv window: xi(l-3..l-1)

    const int base = bn * L;
    const int last = base + L - 1;

#define LOADS(tk, dt_, xi_, Ba_, Bb_, Ca_, Cb_, z_)                      \
    dt_ = dty[(size_t)(tk) * 512 + e];                                   \
    xi_ = xz [(size_t)(tk) * 1024 + e];                                  \
    Ba_ = *(const f4*)(dbl + (size_t)(tk) * 48 + 16 + sh);               \
    Bb_ = *(const f4*)(dbl + (size_t)(tk) * 48 + 20 + sh);               \
    Ca_ = *(const f4*)(dbl + (size_t)(tk) * 48 + 32 + sh);               \
    Cb_ = *(const f4*)(dbl + (size_t)(tk) * 48 + 36 + sh);               \
    z_  = xz [(size_t)(tk) * 1024 + 512 + e];

#define COMPUTE(tk, dt_, xi_, Ba_, Bb_, Ca_, Cb_, z_)                    \
    {                                                                    \
        float u = cbe;                                                   \
        u = fmaf(w0, cwe[0], u);                                         \
        u = fmaf(w1, cwe[1], u);                                         \
        u = fmaf(w2, cwe[2], u);                                         \
        u = fmaf(xi_, cwe[3], u);                                        \
        u = silu_f(u);                                                   \
        w0 = w1; w1 = w2; w2 = xi_;                                      \
        float y = 0.0f;                                                  \
        float du = (dt_) * u;                                            \
        _Pragma("unroll")                                                \
        for (int s = 0; s < 4; s++) {                                    \
            float dA = __expf((dt_) * Ae[s]);                            \
            h[s] = fmaf(dA, h[s], du * (Ba_)[s]);                        \
            y    = fmaf(h[s], (Ca_)[s], y);                              \
        }                                                                \
        _Pragma("unroll")                                                \
        for (int s = 0; s < 4; s++) {                                    \
            float dA = __expf((dt_) * Ae[4 + s]);                        \
            h[4 + s] = fmaf(dA, h[4 + s], du * (Bb_)[s]);                \
            y        = fmaf(h[4 + s], (Cb_)[s], y);                      \
        }                                                                \
        y += __shfl_xor(y, 1);                                           \
        if (sh == 0)                                                     \
            dty[(size_t)(tk) * 512 + e] = (y + u * De) * silu_f(z_);     \
    }

#define REFILL(slot_tk, dt_, xi_, Ba_, Bb_, Ca_, Cb_, z_)                \
    {                                                                    \
        int tp = (slot_tk) > last ? last : (slot_tk);                    \
        LOADS(tp, dt_, xi_, Ba_, Bb_, Ca_, Cb_, z_);                     \
    }

    float dt0, x0, z0, dt1, x1, z1, dt2, x2, z2, dt3, x3, z3;
    f4 Ba0, Bb0, Ca0, Cb0, Ba1, Bb1, Ca1, Cb1;
    f4 Ba2, Bb2, Ca2, Cb2, Ba3, Bb3, Ca3, Cb3;
    LOADS(base,     dt0, x0, Ba0, Bb0, Ca0, Cb0, z0);
    LOADS(base + 1, dt1, x1, Ba1, Bb1, Ca1, Cb1, z1);
    LOADS(base + 2, dt2, x2, Ba2, Bb2, Ca2, Cb2, z2);
    LOADS(base + 3, dt3, x3, Ba3, Bb3, Ca3, Cb3, z3);

    for (int l = 0; l < L; l += 4) {
        int tk = base + l;
        COMPUTE(tk,     dt0, x0, Ba0, Bb0, Ca0, Cb0, z0);
        REFILL(tk + 4,  dt0, x0, Ba0, Bb0, Ca0, Cb0, z0);
        COMPUTE(tk + 1, dt1, x1, Ba1, Bb1, Ca1, Cb1, z1);
        REFILL(tk + 5,  dt1, x1, Ba1, Bb1, Ca1, Cb1, z1);
        COMPUTE(tk + 2, dt2, x2, Ba2, Bb2, Ca2, Cb2, z2);
        REFILL(tk + 6,  dt2, x2, Ba2, Bb2, Ca2, Cb2, z2);
        COMPUTE(tk + 3, dt3, x3, Ba3, Bb3, Ca3, Cb3, z3);
        REFILL(tk + 7,  dt3, x3, Ba3, Bb3, Ca3, Cb3, z3);
    }
#undef LOADS
#undef COMPUTE
#undef REFILL
}

// ---------------------------------------------------------------------------
// One mamba stage (weights pre-transposed to k-major; conv fused into
// xproj_dt_conv staging and scan; no xc buffer, no conv kernel).
// ---------------------------------------------------------------------------
template<int OUTMODE>
static void run_stage(const float* xin,
                      const float* in_wT, const float* conv_w, const float* conv_b,
                      const float* xproj_w, const float* dt_w, const float* dt_b,
                      const float* A_log, const float* Dvec, const float* out_wT,
                      float* xz, float* dbl, float* dty, float* outp,
                      int Bn, int L, hipStream_t stream)
{
    const int M = TOKENS;
    // in_proj: [M,1024] = x[M,256] * in_w^T   (BN=256, BK=8, grid 384x4)
    gemm_v6<256, 256, 8, 0><<<dim3(M / 32, 1024 / 256), 256, 0, stream>>>(xin, in_wT, xz, 1024);
    // fused conv + x_proj + dt_proj (384 blocks)
    xproj_dt_conv<<<dim3(M / 32), 256, 0, stream>>>(
        xz, conv_w, conv_b, xproj_w, dt_w, dt_b, dbl, dty, M, L);
    // scan + skip + gate with fused conv (state-split 2x, depth-4 prefetch)
    scan_gate8c<<<dim3(Bn * 4), 256, 0, stream>>>(dty, xz, dbl, conv_w, conv_b,
                                                  A_log, Dvec, L);
    // out_proj with fused layout transpose (BN=128, BK=32, grid 384x2)
    gemm_v6<512, 128, 32, OUTMODE><<<dim3(M / 32, 256 / 128), 256, 0, stream>>>(dty, out_wT, outp, 256);
}

extern "C" void kernel_launch(void* const* d_in, const int* in_sizes, int n_in,
                              void* d_out, int out_size, void* d_ws, size_t ws_size,
                              hipStream_t stream)
{
    const float* x = (const float*)d_in[0];
    const float* t_in_w    = (const float*)d_in[1];
    const float* t_conv_w  = (const float*)d_in[2];
    const float* t_conv_b  = (const float*)d_in[3];
    const float* t_xproj_w = (const float*)d_in[4];
    const float* t_dt_w    = (const float*)d_in[5];
    const float* t_dt_b    = (const float*)d_in[6];
    const float* t_A_log   = (const float*)d_in[7];
    const float* t_D       = (const float*)d_in[8];
    const float* t_out_w   = (const float*)d_in[9];
    const float* d_in_w    = (const float*)d_in[10];
    const float* d_conv_w  = (const float*)d_in[11];
    const float* d_conv_b  = (const float*)d_in[12];
    const float* d_xproj_w = (const float*)d_in[13];
    const float* d_dt_w    = (const float*)d_in[14];
    const float* d_dt_b    = (const float*)d_in[15];
    const float* d_A_log   = (const float*)d_in[16];
    const float* d_D       = (const float*)d_in[17];
    const float* d_out_w   = (const float*)d_in[18];

    float* ws  = (float*)d_ws;
    float* xz  = ws;                                  // 12288*1024
    float* dbl = xz  + (size_t)TOKENS * 1024;         // 12288*48
    float* dty = dbl + (size_t)TOKENS * 48;           // 12288*512
    float* xt  = dty + (size_t)TOKENS * 512;          // 12288*256
    float* t_in_wT  = xt + (size_t)TOKENS * 256;      // [256][1024]
    float* t_out_wT = t_in_wT  + 262144;              // [512][256]
    float* d_in_wT  = t_out_wT + 131072;              // [256][1024]
    float* d_out_wT = d_in_wT  + 262144;              // [512][256]
    const size_t need_bytes =
        ((size_t)TOKENS * (1024 + 48 + 512 + 256) + 2 * (262144 + 131072)) * 4;
    if (ws_size < need_bytes) return;

    // pre-transpose the four big weights to k-major (batched: 2 dispatches)
    transpose_w2<<<dim3(256 / 32, 1024 / 32, 2), 256, 0, stream>>>(
        t_in_w, t_in_wT, d_in_w, d_in_wT, 1024, 256);
    transpose_w2<<<dim3(512 / 32, 256 / 32, 2), 256, 0, stream>>>(
        t_out_w, t_out_wT, d_out_w, d_out_wT, 256, 512);

    // stage 1: time scan, Bn = 128, L = 96
    run_stage<2>(x, t_in_wT, t_conv_w, t_conv_b, t_xproj_w, t_dt_w, t_dt_b,
                 t_A_log, t_D, t_out_wT, xz, dbl, dty, xt,
                 NB * NVAR, SEG, stream);
    // stage 2: dimension scan, Bn = 384, L = 32
    run_stage<3>(xt, d_in_wT, d_conv_w, d_conv_b, d_xproj_w, d_dt_w, d_dt_b,
                 d_A_log, d_D, d_out_wT, xz, dbl, dty, (float*)d_out,
                 NB * SEG, NVAR, stream);
}

// Round 20
// 437.924 us; speedup vs baseline: 1.0994x; 1.0422x over previous
//
#include <hip/hip_runtime.h>
#include <hip/hip_bf16.h>
#include <math.h>

#define D_MODEL 256
#define D_STATE 16
#define D_INNER 512
#define DT_RANK 16
#define NB 4
#define NVAR 32
#define SEG 96
#define TOKENS (NB*NVAR*SEG)   /* 12288 */

typedef float f4 __attribute__((ext_vector_type(4)));

__device__ __forceinline__ float silu_f(float x) { return x / (1.0f + __expf(-x)); }

// ---------------------------------------------------------------------------
// Batched transpose: z in {0,1} picks (W0->WT0) or (W1->WT1).  W: [N][K].
// grid (K/32, N/32, 2), block 256.
// ---------------------------------------------------------------------------
__global__ __launch_bounds__(256)
void transpose_w2(const float* __restrict__ W0, float* __restrict__ WT0,
                  const float* __restrict__ W1, float* __restrict__ WT1,
                  int N, int K)
{
    const float* W  = blockIdx.z ? W1  : W0;
    float*       WT = blockIdx.z ? WT1 : WT0;
    __shared__ float t[32][33];
    const int k0 = blockIdx.x * 32, n0 = blockIdx.y * 32;
    const int tx = threadIdx.x & 31, ty = threadIdx.x >> 5;
#pragma unroll
    for (int i = 0; i < 32; i += 8)
        t[ty + i][tx] = W[(size_t)(n0 + ty + i) * K + k0 + tx];
    __syncthreads();
#pragma unroll
    for (int i = 0; i < 32; i += 8)
        WT[(size_t)(k0 + ty + i) * N + n0 + tx] = t[tx][ty + i];
}

// ---------------------------------------------------------------------------
// NT GEMM v6 (round-15 proven config): C[m,n] = sum_k A[m,k]*WT[k][n].
// 256 thr = 4 waves; BM=32 (wave owns 8 rows; A wave-uniform -> s_load).
// W: coalesced global_load_lds DMA into linear LDS [BK][BN], double-buffered,
// one barrier per K-tile.  Plateau ~53% of fp32 peak -- verified optimal over
// BK{8,16,32}, BN{128,256}, BM{32,64}, A-path{s_load,VMEM,LDS}, pipelining.
// MODE 0 plain; 2: rows (b,v,s)->(b,s,v); 3: inverse.
// ---------------------------------------------------------------------------
template<int K, int BN, int BK, int MODE>
__global__ __launch_bounds__(256, 4)
void gemm_v6(const float* __restrict__ A, const float* __restrict__ WT,
             float* __restrict__ C, int N)
{
    constexpr int NT  = K / BK;
    constexpr int CPL = BN / 64;
    constexpr int KRD = 1024 / (BN * 4);
    constexpr int J   = BK / (KRD * 4);
    typedef float cvec __attribute__((ext_vector_type(CPL)));
    __shared__ float wlds[2 * BK * BN];

    const int tid  = threadIdx.x;
    const int lane = tid & 63;
    const int wid  = __builtin_amdgcn_readfirstlane(tid >> 6);
    const int m0 = blockIdx.x * 32;
    const int n0 = blockIdx.y * BN;

    const float* Ar[8];
#pragma unroll
    for (int r = 0; r < 8; r++)
        Ar[r] = A + (size_t)(m0 + wid * 8 + r) * K;

    auto stage = [&](int dbuf, int k0) {
#pragma unroll
        for (int j = 0; j < J; j++) {
            int kb   = (wid * J + j) * KRD;
            int krow = kb + ((KRD == 2) ? (lane >> 5) : 0);
            int nofs = ((KRD == 2) ? (lane & 31) : lane) * 4;
            int dstw = __builtin_amdgcn_readfirstlane(dbuf * (BK * BN) + kb * BN);
            __builtin_amdgcn_global_load_lds(
                (const __attribute__((address_space(1))) void*)
                    (WT + (size_t)(k0 + krow) * N + n0 + nofs),
                (__attribute__((address_space(3))) void*)(wlds + dstw), 16, 0, 0);
        }
    };

    float acc[8][CPL];
#pragma unroll
    for (int r = 0; r < 8; r++)
#pragma unroll
        for (int g = 0; g < CPL; g++) acc[r][g] = 0.0f;

    stage(0, 0);
    __syncthreads();

    for (int t = 0; t < NT; t++) {
        const int k0 = t * BK;
        if (t + 1 < NT) stage((t + 1) & 1, k0 + BK);
        const float* Wb = wlds + (t & 1) * (BK * BN);
#pragma unroll
        for (int q = 0; q < BK / 4; q++) {
            f4 a4[8];
#pragma unroll
            for (int r = 0; r < 8; r++)
                a4[r] = *(const f4*)(Ar[r] + k0 + 4 * q);
#pragma unroll
            for (int e = 0; e < 4; e++) {
                cvec wv = *(const cvec*)(Wb + (4 * q + e) * BN + CPL * lane);
#pragma unroll
                for (int r = 0; r < 8; r++)
#pragma unroll
                    for (int g = 0; g < CPL; g++)
                        acc[r][g] = fmaf(a4[r][e], wv[g], acc[r][g]);
            }
        }
        __syncthreads();
    }

#pragma unroll
    for (int r = 0; r < 8; r++) {
        int m = m0 + wid * 8 + r;
        int orow = m;
        if (MODE == 2) {                         // (b*32+v)*96+s -> (b*96+s)*32+v
            int b = m / 3072, rr = m % 3072;
            int v = rr / 96, s = rr % 96;
            orow = (b * 96 + s) * 32 + v;
        } else if (MODE == 3) {                  // (b*96+s)*32+v -> (b*32+v)*96+s
            int b = m / 3072, rr = m % 3072;
            int s = rr / 32, v = rr % 32;
            orow = (b * 32 + v) * 96 + s;
        }
        cvec v;
#pragma unroll
        for (int g = 0; g < CPL; g++) v[g] = acc[r][g];
        *(cvec*)(C + (size_t)orow * N + n0 + CPL * lane) = v;
    }
}

// ---------------------------------------------------------------------------
// Fused conv + x_proj + dt_proj, BM=16 retile (r19 had BM=32: grid 384 =
// 1.5 blocks/CU, occupancy 14.7%, latency-bound; +4-way As-write conflicts).
// Grid 768 = 3 blocks/CU; As stride 17 -> write banks (17k+r)%32 spread,
// <=2-way (free).  16 | L (96, 32) so a tile never crosses a sequence.
// Phase 1: dbl[16][48] = conv-staged-A[16][512] * xpw^T (+ global store).
// Phase 2: dty = softplus(dbl[:, :16] * dtw^T + dtb).
// ---------------------------------------------------------------------------
__global__ __launch_bounds__(256)
void xproj_dt_conv(const float* __restrict__ xz,   // [M][1024]
                   const float* __restrict__ cw,   // [512][4]
                   const float* __restrict__ cb,   // [512]
                   const float* __restrict__ xpw,  // [48][512]
                   const float* __restrict__ dtw,  // [512][16]
                   const float* __restrict__ dtb,  // [512]
                   float* __restrict__ dbl,        // [M][48]
                   float* __restrict__ dty,        // [M][512]
                   int M, int L)
{
    constexpr int BM = 16, BN = 64, BK = 32, TN = 4;
    __shared__ float As[BK][BM + 1];             // stride 17: conflict-free
    __shared__ float Ws[BK][BN + 4];
    __shared__ float dbl_s[BM][52];

    const int tid = threadIdx.x;
    const int tx  = tid % (BN / TN);             // 0..15 (col group)
    const int ty  = tid / (BN / TN);             // 0..15 (row)
    const int m0  = blockIdx.x * BM;
    const int lmb = m0 % L;

    // conv staging role (tid < 128): row = tid>>3, kc = (tid&7)*4
    const int s_row = tid >> 3;
    const int s_kc  = (tid & 7) << 2;
    const int s_m   = m0 + s_row;
    const int s_lm  = lmb + s_row;

    float acc[TN];
#pragma unroll
    for (int j = 0; j < TN; j++) acc[j] = 0.0f;

    constexpr int WF4 = (BN * BK) / 1024;        // 2
    constexpr int F4R = BK / 4;

    for (int k0 = 0; k0 < 512; k0 += BK) {
        // --- fused conv staging of As (tid<128): 4 xz rows, 4 taps, SiLU ---
        if (tid < 128) {
            const int col0 = k0 + s_kc;
            f4 xv[4];
#pragma unroll
            for (int j = 0; j < 4; j++) {
                if (s_lm - 3 + j >= 0)
                    xv[j] = *(const f4*)(xz + (size_t)(s_m - 3 + j) * 1024 + col0);
                else
                    xv[j] = (f4)0.0f;
            }
            f4 bv = *(const f4*)(cb + col0);
#pragma unroll
            for (int c = 0; c < 4; c++) {
                f4 w = *(const f4*)(cw + (size_t)(col0 + c) * 4);
                float v = bv[c];
#pragma unroll
                for (int j = 0; j < 4; j++)
                    v = fmaf(xv[j][c], w[j], v);
                As[s_kc + c][s_row] = silu_f(v);
            }
        }
        // --- W staging (xpw) ---
#pragma unroll
        for (int c = 0; c < WF4; c++) {
            int idx = tid + c * 256;
            int row = idx / F4R;
            int kc  = (idx % F4R) * 4;
            float4 v;
            if (row < 48) v = *(const float4*)(xpw + (size_t)row * 512 + k0 + kc);
            else          v = make_float4(0.f, 0.f, 0.f, 0.f);
            Ws[kc + 0][row] = v.x;
            Ws[kc + 1][row] = v.y;
            Ws[kc + 2][row] = v.z;
            Ws[kc + 3][row] = v.w;
        }
        __syncthreads();

#pragma unroll
        for (int kk = 0; kk < BK; kk++) {
            float a = As[kk][ty];
            float w[TN];
#pragma unroll
            for (int j = 0; j < TN; j++) w[j] = Ws[kk][tx * TN + j];
#pragma unroll
            for (int j = 0; j < TN; j++)
                acc[j] = fmaf(a, w[j], acc[j]);
        }
        __syncthreads();
    }

    // store dbl tile: global (scan reads B,C) + LDS (dt phase)
#pragma unroll
    for (int j = 0; j < TN; j++) {
        int n = tx * TN + j;
        if (n < 48) {
            dbl[(size_t)(m0 + ty) * 48 + n] = acc[j];
            dbl_s[ty][n] = acc[j];
        }
    }
    __syncthreads();

    // dt phase: cols n = tid and tid+256; K=16 from LDS (broadcast reads)
    f4 wA[4], wB[4];
#pragma unroll
    for (int c = 0; c < 4; c++) {
        wA[c] = *(const f4*)(dtw + (size_t)tid * 16 + 4 * c);
        wB[c] = *(const f4*)(dtw + (size_t)(tid + 256) * 16 + 4 * c);
    }
    const float bA = dtb[tid], bB = dtb[tid + 256];
#pragma unroll 4
    for (int r = 0; r < BM; r++) {
        f4 d[4];
#pragma unroll
        for (int c = 0; c < 4; c++) d[c] = *(const f4*)(&dbl_s[r][4 * c]);
        float vA = bA, vB = bB;
#pragma unroll
        for (int c = 0; c < 4; c++)
#pragma unroll
            for (int e = 0; e < 4; e++) {
                vA = fmaf(d[c][e], wA[c][e], vA);
                vB = fmaf(d[c][e], wB[c][e], vB);
            }
        vA = (vA > 20.0f) ? vA : log1pf(__expf(vA));
        vB = (vB > 20.0f) ? vB : log1pf(__expf(vB));
        dty[(size_t)(m0 + r) * 512 + tid]       = vA;
        dty[(size_t)(m0 + r) * 512 + tid + 256] = vB;
    }
}

// ---------------------------------------------------------------------------
// Selective scan + skip + gate, 2-way state split (8 states/thread),
// depth-4 named-slot prefetch, conv fused via 3-register rolling window.
// L % 4 == 0 (96, 32).
// ---------------------------------------------------------------------------
__global__ __launch_bounds__(256, 4)
void scan_gate8c(float* __restrict__ dty,
                 const float* __restrict__ xz,
                 const float* __restrict__ dbl,
                 const float* __restrict__ cw,
                 const float* __restrict__ cb,
                 const float* __restrict__ A_log,
                 const float* __restrict__ Dvec,
                 int L)
{
    int bn = blockIdx.x >> 2;
    int e  = ((blockIdx.x & 3) << 7) + (threadIdx.x >> 1);
    int sh = (threadIdx.x & 1) << 3;       // state half: 0 or 8

    float Ae[8], h[8];
#pragma unroll
    for (int s = 0; s < 8; s++) {
        Ae[s] = -__expf(A_log[e * D_STATE + sh + s]);
        h[s]  = 0.0f;
    }
    const float De  = Dvec[e];
    const f4 cwe    = *(const f4*)(cw + (size_t)e * 4);
    const float cbe = cb[e];
    float w0 = 0.f, w1 = 0.f, w2 = 0.f;    // conv window: xi(l-3..l-1)

    const int base = bn * L;
    const int last = base + L - 1;

#define LOADS(tk, dt_, xi_, Ba_, Bb_, Ca_, Cb_, z_)                      \
    dt_ = dty[(size_t)(tk) * 512 + e];                                   \
    xi_ = xz [(size_t)(tk) * 1024 + e];                                  \
    Ba_ = *(const f4*)(dbl + (size_t)(tk) * 48 + 16 + sh);               \
    Bb_ = *(const f4*)(dbl + (size_t)(tk) * 48 + 20 + sh);               \
    Ca_ = *(const f4*)(dbl + (size_t)(tk) * 48 + 32 + sh);               \
    Cb_ = *(const f4*)(dbl + (size_t)(tk) * 48 + 36 + sh);               \
    z_  = xz [(size_t)(tk) * 1024 + 512 + e];

#define COMPUTE(tk, dt_, xi_, Ba_, Bb_, Ca_, Cb_, z_)                    \
    {                                                                    \
        float u = cbe;                                                   \
        u = fmaf(w0, cwe[0], u);                                         \
        u = fmaf(w1, cwe[1], u);                                         \
        u = fmaf(w2, cwe[2], u);                                         \
        u = fmaf(xi_, cwe[3], u);                                        \
        u = silu_f(u);                                                   \
        w0 = w1; w1 = w2; w2 = xi_;                                      \
        float y = 0.0f;                                                  \
        float du = (dt_) * u;                                            \
        _Pragma("unroll")                                                \
        for (int s = 0; s < 4; s++) {                                    \
            float dA = __expf((dt_) * Ae[s]);                            \
            h[s] = fmaf(dA, h[s], du * (Ba_)[s]);                        \
            y    = fmaf(h[s], (Ca_)[s], y);                              \
        }                                                                \
        _Pragma("unroll")                                                \
        for (int s = 0; s < 4; s++) {                                    \
            float dA = __expf((dt_) * Ae[4 + s]);                        \
            h[4 + s] = fmaf(dA, h[4 + s], du * (Bb_)[s]);                \
            y        = fmaf(h[4 + s], (Cb_)[s], y);                      \
        }                                                                \
        y += __shfl_xor(y, 1);                                           \
        if (sh == 0)                                                     \
            dty[(size_t)(tk) * 512 + e] = (y + u * De) * silu_f(z_);     \
    }

#define REFILL(slot_tk, dt_, xi_, Ba_, Bb_, Ca_, Cb_, z_)                \
    {                                                                    \
        int tp = (slot_tk) > last ? last : (slot_tk);                    \
        LOADS(tp, dt_, xi_, Ba_, Bb_, Ca_, Cb_, z_);                     \
    }

    float dt0, x0, z0, dt1, x1, z1, dt2, x2, z2, dt3, x3, z3;
    f4 Ba0, Bb0, Ca0, Cb0, Ba1, Bb1, Ca1, Cb1;
    f4 Ba2, Bb2, Ca2, Cb2, Ba3, Bb3, Ca3, Cb3;
    LOADS(base,     dt0, x0, Ba0, Bb0, Ca0, Cb0, z0);
    LOADS(base + 1, dt1, x1, Ba1, Bb1, Ca1, Cb1, z1);
    LOADS(base + 2, dt2, x2, Ba2, Bb2, Ca2, Cb2, z2);
    LOADS(base + 3, dt3, x3, Ba3, Bb3, Ca3, Cb3, z3);

    for (int l = 0; l < L; l += 4) {
        int tk = base + l;
        COMPUTE(tk,     dt0, x0, Ba0, Bb0, Ca0, Cb0, z0);
        REFILL(tk + 4,  dt0, x0, Ba0, Bb0, Ca0, Cb0, z0);
        COMPUTE(tk + 1, dt1, x1, Ba1, Bb1, Ca1, Cb1, z1);
        REFILL(tk + 5,  dt1, x1, Ba1, Bb1, Ca1, Cb1, z1);
        COMPUTE(tk + 2, dt2, x2, Ba2, Bb2, Ca2, Cb2, z2);
        REFILL(tk + 6,  dt2, x2, Ba2, Bb2, Ca2, Cb2, z2);
        COMPUTE(tk + 3, dt3, x3, Ba3, Bb3, Ca3, Cb3, z3);
        REFILL(tk + 7,  dt3, x3, Ba3, Bb3, Ca3, Cb3, z3);
    }
#undef LOADS
#undef COMPUTE
#undef REFILL
}

// ---------------------------------------------------------------------------
// One mamba stage (weights pre-transposed; conv fused; no xc buffer).
// ---------------------------------------------------------------------------
template<int OUTMODE>
static void run_stage(const float* xin,
                      const float* in_wT, const float* conv_w, const float* conv_b,
                      const float* xproj_w, const float* dt_w, const float* dt_b,
                      const float* A_log, const float* Dvec, const float* out_wT,
                      float* xz, float* dbl, float* dty, float* outp,
                      int Bn, int L, hipStream_t stream)
{
    const int M = TOKENS;
    // in_proj: [M,1024] = x[M,256] * in_w^T   (BN=256, BK=8, grid 384x4)
    gemm_v6<256, 256, 8, 0><<<dim3(M / 32, 1024 / 256), 256, 0, stream>>>(xin, in_wT, xz, 1024);
    // fused conv + x_proj + dt_proj (768 blocks)
    xproj_dt_conv<<<dim3(M / 16), 256, 0, stream>>>(
        xz, conv_w, conv_b, xproj_w, dt_w, dt_b, dbl, dty, M, L);
    // scan + skip + gate with fused conv (state-split 2x, depth-4 prefetch)
    scan_gate8c<<<dim3(Bn * 4), 256, 0, stream>>>(dty, xz, dbl, conv_w, conv_b,
                                                  A_log, Dvec, L);
    // out_proj with fused layout transpose (BN=128, BK=32, grid 384x2)
    gemm_v6<512, 128, 32, OUTMODE><<<dim3(M / 32, 256 / 128), 256, 0, stream>>>(dty, out_wT, outp, 256);
}

extern "C" void kernel_launch(void* const* d_in, const int* in_sizes, int n_in,
                              void* d_out, int out_size, void* d_ws, size_t ws_size,
                              hipStream_t stream)
{
    const float* x = (const float*)d_in[0];
    const float* t_in_w    = (const float*)d_in[1];
    const float* t_conv_w  = (const float*)d_in[2];
    const float* t_conv_b  = (const float*)d_in[3];
    const float* t_xproj_w = (const float*)d_in[4];
    const float* t_dt_w    = (const float*)d_in[5];
    const float* t_dt_b    = (const float*)d_in[6];
    const float* t_A_log   = (const float*)d_in[7];
    const float* t_D       = (const float*)d_in[8];
    const float* t_out_w   = (const float*)d_in[9];
    const float* d_in_w    = (const float*)d_in[10];
    const float* d_conv_w  = (const float*)d_in[11];
    const float* d_conv_b  = (const float*)d_in[12];
    const float* d_xproj_w = (const float*)d_in[13];
    const float* d_dt_w    = (const float*)d_in[14];
    const float* d_dt_b    = (const float*)d_in[15];
    const float* d_A_log   = (const float*)d_in[16];
    const float* d_D       = (const float*)d_in[17];
    const float* d_out_w   = (const float*)d_in[18];

    float* ws  = (float*)d_ws;
    float* xz  = ws;                                  // 12288*1024
    float* dbl = xz  + (size_t)TOKENS * 1024;         // 12288*48
    float* dty = dbl + (size_t)TOKENS * 48;           // 12288*512
    float* xt  = dty + (size_t)TOKENS * 512;          // 12288*256
    float* t_in_wT  = xt + (size_t)TOKENS * 256;      // [256][1024]
    float* t_out_wT = t_in_wT  + 262144;              // [512][256]
    float* d_in_wT  = t_out_wT + 131072;              // [256][1024]
    float* d_out_wT = d_in_wT  + 262144;              // [512][256]
    const size_t need_bytes =
        ((size_t)TOKENS * (1024 + 48 + 512 + 256) + 2 * (262144 + 131072)) * 4;
    if (ws_size < need_bytes) return;

    // pre-transpose the four big weights to k-major (batched: 2 dispatches)
    transpose_w2<<<dim3(256 / 32, 1024 / 32, 2), 256, 0, stream>>>(
        t_in_w, t_in_wT, d_in_w, d_in_wT, 1024, 256);
    transpose_w2<<<dim3(512 / 32, 256 / 32, 2), 256, 0, stream>>>(
        t_out_w, t_out_wT, d_out_w, d_out_wT, 256, 512);

    // stage 1: time scan, Bn = 128, L = 96
    run_stage<2>(x, t_in_wT, t_conv_w, t_conv_b, t_xproj_w, t_dt_w, t_dt_b,
                 t_A_log, t_D, t_out_wT, xz, dbl, dty, xt,
                 NB * NVAR, SEG, stream);
    // stage 2: dimension scan, Bn = 384, L = 32
    run_stage<3>(xt, d_in_wT, d_conv_w, d_conv_b, d_xproj_w, d_dt_w, d_dt_b,
                 d_A_log, d_D, d_out_wT, xz, dbl, dty, (float*)d_out,
                 NB * SEG, NVAR, stream);
}